// Round 8
// baseline (2294.742 us; speedup 1.0000x reference)
//
#include <hip/hip_runtime.h>

#define B_DIM 2048
#define K_DIM 8192
#define N_DIM 8192
#define NNZ_N 4194304

#define BM 128
#define BN 128
#define BK 64

typedef __attribute__((ext_vector_type(8))) short short8;
typedef __attribute__((ext_vector_type(4))) float f32x4;
typedef __attribute__((ext_vector_type(4))) unsigned short u16x4;

typedef __attribute__((address_space(1))) void gvoid_t;
typedef __attribute__((address_space(3))) void svoid_t;

__device__ __forceinline__ unsigned short f2bf(float f) {
  unsigned u = __float_as_uint(f);
  unsigned r = 0x7fffu + ((u >> 16) & 1u);
  return (unsigned short)((u + r) >> 16);
}
__device__ __forceinline__ float bf2f(unsigned short h) {
  return __uint_as_float(((unsigned)h) << 16);
}

// Add bf16 value v into one 16-bit half of the u32 at p (pair-aligned).
// CAS loop: guaranteed-compile, correct for duplicates; contention ~0 so
// ~1 iteration typical. Cost is the random 128B-line RMW traffic, same as
// the native pk-atomic would pay.
__device__ __forceinline__ void pk_add_bf16(unsigned short* p, unsigned short v,
                                            int half) {
  unsigned int* pu = (unsigned int*)p;
  unsigned int old = *pu, assumed;
  do {
    assumed = old;
    unsigned short cur =
        half ? (unsigned short)(assumed >> 16) : (unsigned short)(assumed & 0xffffu);
    unsigned short sum = f2bf(bf2f(cur) + bf2f(v));
    unsigned int nw = half ? ((assumed & 0x0000ffffu) | ((unsigned)sum << 16))
                           : ((assumed & 0xffff0000u) | (unsigned)sum);
    old = atomicCAS(pu, assumed, nw);
  } while (old != assumed);
}

// --- single-pass scatter: COO entry -> bf16 hi/lo planes [N_DIM][K_DIM].
// Per entry: hi=bf16(v), lo=bf16(v-hi); atomically bf16-add into the planes.
// Singles (99.9% of slots, planes zeroed) are bit-identical to the fp32
// scatter+split pipeline (x+0 exact in bf16); duplicates add <=~1e-3 rounding.
__global__ __launch_bounds__(256) void scatter_pk_kernel(
    const int* __restrict__ idx, const float* __restrict__ vals,
    unsigned short* __restrict__ Whi, unsigned short* __restrict__ Wlo) {
  int i = blockIdx.x * 256 + threadIdx.x;   // NNZ divisible by 256
  int r = idx[i];
  int c = idx[NNZ_N + i];
  float v = vals[i];
  unsigned short h = f2bf(v);
  unsigned short l = f2bf(v - bf2f(h));
  size_t base = (size_t)r * K_DIM + (size_t)(c & ~1);
  int half = c & 1;
  pk_add_bf16(Whi + base, h, half);
  pk_add_bf16(Wlo + base, l, half);
}

// --- split fp32 -> (hi, lo) bf16, 4 elems/thread; count divisible by 1024
__global__ __launch_bounds__(256) void split_kernel(
    const float* __restrict__ src, unsigned short* __restrict__ hi,
    unsigned short* __restrict__ lo) {
  size_t i = (size_t)blockIdx.x * 256 + threadIdx.x;
  f32x4 v = ((const f32x4*)src)[i];
  u16x4 h, l;
#pragma unroll
  for (int j = 0; j < 4; ++j) {
    float f = v[j];
    unsigned short hb = f2bf(f);
    float lf = f - bf2f(hb);
    h[j] = hb;
    l[j] = f2bf(lf);
  }
  ((u16x4*)hi)[i] = h;
  ((u16x4*)lo)[i] = l;
}

// --- legacy fp32 chunk scatter (Tier B fallback only)
__global__ __launch_bounds__(256) void scatter_kernel(
    const int* __restrict__ idx, const float* __restrict__ vals,
    float* __restrict__ Wc, int r0, int rows) {
  int i = blockIdx.x * 256 + threadIdx.x;
  int r = idx[i] - r0;
  if ((unsigned)r < (unsigned)rows) {
    int c = idx[NNZ_N + i];
    unsafeAtomicAdd(&Wc[(size_t)r * K_DIM + c], vals[i]);
  }
}

// --- fused 3-phase split-bf16 GEMM: C = Xhi*Whi^T + Xhi*Wlo^T + Xlo*Whi^T
// m97-structure: 128x128 tile, BK=64, 4 waves (2x2 of 64x64), 16x16x32 bf16
// MFMA, global_load_lds width-16 staging, 2-barrier K loop.
// Measured r5/r7: 508 us = 1.62 PF = 65% dense peak; FETCH 490 MB ~= minimal.
struct GemmCtx {
  size_t aoff[4], boff[4];
  int wr, wc, fr, fk;
};

__device__ __forceinline__ void gemm_phase(
    const unsigned short* __restrict__ Ap, const unsigned short* __restrict__ Bp,
    unsigned short* As, unsigned short* Bs, const GemmCtx& c, int wid,
    f32x4 acc[4][4]) {
  for (int kt = 0; kt < K_DIM / BK; ++kt) {
    const int k0 = kt * BK;
#pragma unroll
    for (int i = 0; i < 4; ++i) {
      int ch = wid * 4 + i;
      __builtin_amdgcn_global_load_lds(
          (const gvoid_t*)(Ap + c.aoff[i] + k0),
          (svoid_t*)(As + ch * 512), 16, 0, 0);
      __builtin_amdgcn_global_load_lds(
          (const gvoid_t*)(Bp + c.boff[i] + k0),
          (svoid_t*)(Bs + ch * 512), 16, 0, 0);
    }
    __syncthreads();

#pragma unroll
    for (int ks = 0; ks < 2; ++ks) {
      short8 a[4], b[4];
#pragma unroll
      for (int m = 0; m < 4; ++m)
        a[m] = *(const short8*)&As[(c.wr + m * 16 + c.fr) * BK + ks * 32 + c.fk];
#pragma unroll
      for (int n = 0; n < 4; ++n)
        b[n] = *(const short8*)&Bs[(c.wc + n * 16 + c.fr) * BK + ks * 32 + c.fk];
#pragma unroll
      for (int m = 0; m < 4; ++m)
#pragma unroll
        for (int n = 0; n < 4; ++n)
          acc[m][n] = __builtin_amdgcn_mfma_f32_16x16x32_bf16(a[m], b[n], acc[m][n], 0, 0, 0);
    }
    __syncthreads();
  }
}

__global__ __launch_bounds__(256, 2) void gemm_split_kernel(
    const unsigned short* __restrict__ xhi, const unsigned short* __restrict__ xlo,
    const unsigned short* __restrict__ whi, const unsigned short* __restrict__ wlo,
    float* __restrict__ out, int r0, unsigned ntn) {
  __shared__ unsigned short As[BM * BK];  // [128][64] row-major
  __shared__ unsigned short Bs[BN * BK];

  const int tid = threadIdx.x;
  const int lane = tid & 63;
  const int wid = tid >> 6;

  const int tile_m = blockIdx.x / ntn;
  const int tile_n = blockIdx.x % ntn;
  const int m0 = tile_m * BM;
  const int n0 = tile_n * BN;   // chunk-local W row

  const int st_row = lane >> 3;
  const int st_col = (lane & 7) * 8;

  GemmCtx c;
#pragma unroll
  for (int i = 0; i < 4; ++i) {
    int ch = wid * 4 + i;
    c.aoff[i] = (size_t)(m0 + ch * 8 + st_row) * K_DIM + st_col;
    c.boff[i] = (size_t)(n0 + ch * 8 + st_row) * K_DIM + st_col;
  }
  c.fr = lane & 15;            // row within 16x16 frag
  c.fk = (lane >> 4) * 8;      // k offset within 32
  c.wr = (wid >> 1) * 64;      // wave row offset in tile
  c.wc = (wid & 1) * 64;       // wave col offset in tile

  f32x4 acc[4][4];
#pragma unroll
  for (int i = 0; i < 4; ++i)
#pragma unroll
    for (int j = 0; j < 4; ++j) acc[i][j] = (f32x4)0.0f;

  gemm_phase(xhi, whi, As, Bs, c, wid, acc);
  gemm_phase(xhi, wlo, As, Bs, c, wid, acc);
  gemm_phase(xlo, whi, As, Bs, c, wid, acc);

  // epilogue: D layout col=lane&15, row=(lane>>4)*4+reg (m89/m91-verified)
  const int orow = m0 + c.wr + (lane >> 4) * 4;
  const int ocol = r0 + n0 + c.wc + c.fr;
#pragma unroll
  for (int m = 0; m < 4; ++m)
#pragma unroll
    for (int n = 0; n < 4; ++n)
#pragma unroll
      for (int j = 0; j < 4; ++j)
        out[(size_t)(orow + m * 16 + j) * N_DIM + ocol + n * 16] = acc[m][n][j];
}

extern "C" void kernel_launch(void* const* d_in, const int* in_sizes, int n_in,
                              void* d_out, int out_size, void* d_ws, size_t ws_size,
                              hipStream_t stream) {
  const float* x = (const float*)d_in[0];
  const float* vals = (const float*)d_in[1];
  const int* idx = (const int*)d_in[2];
  float* out = (float*)d_out;

  char* ws = (char*)d_ws;
  const size_t MB = 1024ull * 1024ull;

  // x split buffers: 64 MB total (always present)
  unsigned short* Xhi = (unsigned short*)ws;              // 32 MB
  unsigned short* Xlo = (unsigned short*)(ws + 32 * MB);  // 32 MB
  split_kernel<<<(B_DIM * (size_t)K_DIM / 4) / 256, 256, 0, stream>>>(x, Xhi, Xlo);

  if (ws_size >= 320 * MB) {
    // Tier A (single-pass): bf16 planes only, scatter straight into them.
    // Peak 320 MB. Prep = 1 memset + 1 split + 1 scatter.
    unsigned short* Whi = (unsigned short*)(ws + 64 * MB);   // 128 MB
    unsigned short* Wlo = (unsigned short*)(ws + 192 * MB);  // 128 MB (contiguous)
    hipMemsetAsync(Whi, 0, 256 * MB, stream);                // zero both planes
    scatter_pk_kernel<<<NNZ_N / 256, 256, 0, stream>>>(idx, vals, Whi, Wlo);
    gemm_split_kernel<<<(B_DIM / BM) * (N_DIM / BN), 256, 0, stream>>>(
        Xhi, Xlo, Whi, Wlo, out, 0, N_DIM / BN);
  } else {
    // Tier B fallback: fp32 bounce chunks (legacy r5 path).
    int C = 2048;
    while (C > 256 && 64 * MB + (size_t)C * K_DIM * 8 > ws_size) C >>= 1;
    float* Wc = (float*)(ws + 64 * MB);
    unsigned short* WcHi = (unsigned short*)(ws + 64 * MB + (size_t)C * K_DIM * 4);
    unsigned short* WcLo = WcHi + (size_t)C * K_DIM;
    for (int r0 = 0; r0 < N_DIM; r0 += C) {
      hipMemsetAsync(Wc, 0, (size_t)C * K_DIM * sizeof(float), stream);
      scatter_kernel<<<NNZ_N / 256, 256, 0, stream>>>(idx, vals, Wc, r0, C);
      split_kernel<<<((size_t)C * K_DIM / 4) / 256, 256, 0, stream>>>(Wc, WcHi, WcLo);
      gemm_split_kernel<<<(B_DIM / BM) * (C / BN), 256, 0, stream>>>(
          Xhi, Xlo, WcHi, WcLo, out, r0, C / BN);
    }
  }
}